// Round 11
// baseline (506.962 us; speedup 1.0000x reference)
//
#include <hip/hip_runtime.h>
#include <math.h>
#include <stdint.h>

// ============================================================================
// RelationalBlock: 4x (rmsnorm -> attn(mask) -> +res) -> rmsnorm -> SwiGLU -> +res
// B=2 S=1024 D=1024 H=16 hd=64 DFF=4096. All GEMMs bf16-MFMA (fp32 accum).
// Masks index-structured: L0 col j%32==i%32, L1 feat j/128==i/128,
//   L2 nbr |i-j|<=64, L3 full.
// R9 fixes (resubmitted R10 after GPU acquisition timeout):
//  - down-proj SK4 -> SK2 @128x64 (512 blocks): partial traffic 33.5->16.8MB.
//  - QKV tile 64x192 -> 128x96 (same grid, MFMA:ds 1.5->1.71, better A reuse).
//  - 4 transpose kernels -> 1 (28672-block 1D, segment decode).
// Measured so far: gemm swizzle => 0 bank conflicts; gu_swiglu 860 TF (m97
// structure ceiling); no-max softmax + partial-store split-K all verified.
// ============================================================================

typedef __attribute__((ext_vector_type(8))) short bf16x8;
typedef __attribute__((ext_vector_type(4))) float f32x4;
typedef unsigned short ushort_t;
typedef unsigned int uint_t;

#define DEV static __device__ __forceinline__

DEV float bf2f(ushort_t u) { union { uint_t i; float f; } v; v.i = ((uint_t)u) << 16; return v.f; }
DEV ushort_t f2bf(float f) {             // round-to-nearest-even bf16
  union { float f; uint_t i; } v; v.f = f;
  uint_t r = v.i + 0x7fffu + ((v.i >> 16) & 1u);
  return (ushort_t)(r >> 16);
}
DEV uint_t pk2(ushort_t a, ushort_t b) { return (uint_t)a | ((uint_t)b << 16); }

DEV void gld16(const ushort_t* g, ushort_t* l) {   // async global->LDS, 16B/lane
  __builtin_amdgcn_global_load_lds((const __attribute__((address_space(1))) void*)g,
                                   (__attribute__((address_space(3))) void*)l, 16, 0, 0);
}

// ---------------------------------------------------------------------------
// All weight transposes in ONE kernel. fp32 [R][C] -> bf16 [C][R] (B^T form).
// bid segments: [0,16384) qkv/wo 16 mats; [16384,20480) gate; [20480,24576) up;
// [24576,28672) down.
// ---------------------------------------------------------------------------
struct TPtrs { const float* src[19]; };   // 0..15 qkv/wo, 16 gate, 17 up, 18 down

__global__ __launch_bounds__(256) void transpose_all(TPtrs P, ushort_t* __restrict__ qkvT,
    ushort_t* __restrict__ woT, ushort_t* __restrict__ guT, ushort_t* __restrict__ dnT) {
  __shared__ float tile[32][33];
  const int bid = blockIdx.x;
  const float* src; ushort_t* dst; int C, R, bx, by;
  if (bid < 16384) {
    const int mz = bid >> 10, t10 = bid & 1023;
    bx = t10 & 31; by = t10 >> 5;
    src = P.src[mz]; R = 1024; C = 1024;
    const int l = mz >> 2, which = mz & 3;
    dst = (which < 3) ? (qkvT + (size_t)l*3072*1024 + (size_t)which*1024*1024)
                      : (woT  + (size_t)l*1024*1024);
  } else if (bid < 24576) {
    const int seg = (bid - 16384) >> 12;          // 0 gate, 1 up
    const int i = (bid - 16384) & 4095;
    bx = i & 127; by = i >> 7;
    src = P.src[16 + seg]; R = 1024; C = 4096;
    dst = guT + (size_t)seg*4096*1024;
  } else {
    const int i = bid - 24576;
    bx = i & 31; by = i >> 5;
    src = P.src[18]; R = 4096; C = 1024;
    dst = dnT;
  }
  const int tx = threadIdx.x & 31, ty = threadIdx.x >> 5;
  const int r0 = by*32, c0 = bx*32;
#pragma unroll
  for (int i = 0; i < 4; i++) tile[ty + 8*i][tx] = src[(size_t)(r0 + ty + 8*i)*C + c0 + tx];
  __syncthreads();
#pragma unroll
  for (int i = 0; i < 4; i++)
    dst[(size_t)(c0 + ty + 8*i)*R + r0 + tx] = f2bf(tile[tx][ty + 8*i]);
}

// ---------------------------------------------------------------------------
// fused: x = resid + sum_s Pp[s]; write x (fp32); optionally xn = rms(x)*w (bf16)
// ---------------------------------------------------------------------------
template<int NS, int RMS>
__global__ __launch_bounds__(256) void fused_add_rms(
    const float* __restrict__ resid, const float* __restrict__ Pp,
    const float* __restrict__ w, float* __restrict__ xout,
    ushort_t* __restrict__ xn) {
  const int row = blockIdx.x, t = threadIdx.x;
  const size_t off = (size_t)row*1024 + t*4;
  float4 v = *(const float4*)&resid[off];
#pragma unroll
  for (int s = 0; s < NS; s++) {
    const float4 p = *(const float4*)&Pp[(size_t)s*(2048ull*1024) + off];
    v.x += p.x; v.y += p.y; v.z += p.z; v.w += p.w;
  }
  *(float4*)&xout[off] = v;
  if (RMS) {
    float ss = v.x*v.x + v.y*v.y + v.z*v.z + v.w*v.w;
#pragma unroll
    for (int m = 32; m; m >>= 1) ss += __shfl_xor(ss, m);
    __shared__ float red[4];
    if ((t & 63) == 0) red[t >> 6] = ss;
    __syncthreads();
    const float tot = red[0] + red[1] + red[2] + red[3];
    const float rs = rsqrtf(tot * (1.0f/1024.0f) + 1.1920929e-07f);
    const float4 wv = ((const float4*)w)[t];
    uint2 o;
    o.x = pk2(f2bf(v.x*rs*wv.x), f2bf(v.y*rs*wv.y));
    o.y = pk2(f2bf(v.z*rs*wv.z), f2bf(v.w*rs*wv.w));
    *(uint2*)&xn[off] = o;
  }
}

// ---------------------------------------------------------------------------
// GEMM: C[M][N] (+)= A[M][K](bf16) * BT[N][K](bf16)^T. m97 structure + XOR
// chunk swizzle (conflict-free ds_read; source pre-swizzled, LDS linear).
// EPI 0: bf16 store (SPLITK==1). EPI 3: fp32 partial store to slot blockIdx.z.
// Invariant for swizzle: BM/2, BN/2 multiples of 8 (row&7 == l15&7).
// ---------------------------------------------------------------------------
template<int BM, int BN, int EPI, int SPLITK>
__global__ __launch_bounds__(256, 4) void gemm_bt(
    const ushort_t* __restrict__ A, const ushort_t* __restrict__ BT,
    void* __restrict__ Cout, int M, int N, int K) {
  constexpr int BK = 64;
  __shared__ ushort_t Al[BM*BK];
  __shared__ ushort_t Bl[BN*BK];
  const int t = threadIdx.x, lane = t & 63;
  const int l15 = lane & 15, l4 = lane >> 4;
  int bid = blockIdx.y * gridDim.x + blockIdx.x;
  const int nwg = gridDim.x * gridDim.y;
  if ((nwg & 7) == 0) bid = (bid & 7) * (nwg >> 3) + (bid >> 3);
  const int n0 = (bid % gridDim.x) * BN;
  const int m0 = (bid / gridDim.x) * BM;
  constexpr int WM = BM/2, WN = BN/2, FM = WM/16, FN = WN/16;
  const int wm = ((t >> 6) >> 1) * WM;
  const int wn = ((t >> 6) & 1) * WN;
  const f32x4 zf = {0.f, 0.f, 0.f, 0.f};
  f32x4 acc[FM][FN];
#pragma unroll
  for (int m = 0; m < FM; m++)
#pragma unroll
    for (int n = 0; n < FN; n++) acc[m][n] = zf;
  constexpr int CA = (BM*BK)/(256*8), CB = (BN*BK)/(256*8);
  const int kz = blockIdx.z * (K / SPLITK);
  const int sw = l15 & 7;   // read-side XOR key
  for (int k0 = kz; k0 < kz + K / SPLITK; k0 += BK) {
#pragma unroll
    for (int i = 0; i < CA; i++) {
      const int c = i*256 + t, row = c >> 3, ch = (c & 7) ^ (row & 7);
      gld16(&A[(size_t)(m0 + row)*K + k0 + ch*8], &Al[c*8]);
    }
#pragma unroll
    for (int i = 0; i < CB; i++) {
      const int c = i*256 + t, row = c >> 3, ch = (c & 7) ^ (row & 7);
      gld16(&BT[(size_t)(n0 + row)*K + k0 + ch*8], &Bl[c*8]);
    }
    __syncthreads();
#pragma unroll
    for (int kc = 0; kc < BK; kc += 32) {
      bf16x8 af[FM], bfr[FN];
#pragma unroll
      for (int m = 0; m < FM; m++)
        af[m] = *(const bf16x8*)&Al[(wm + m*16 + l15)*BK + (((kc >> 3) + l4) ^ sw)*8];
#pragma unroll
      for (int n = 0; n < FN; n++)
        bfr[n] = *(const bf16x8*)&Bl[(wn + n*16 + l15)*BK + (((kc >> 3) + l4) ^ sw)*8];
#pragma unroll
      for (int m = 0; m < FM; m++)
#pragma unroll
        for (int n = 0; n < FN; n++)
          acc[m][n] = __builtin_amdgcn_mfma_f32_16x16x32_bf16(af[m], bfr[n], acc[m][n], 0, 0, 0);
    }
    __syncthreads();
  }
#pragma unroll
  for (int m = 0; m < FM; m++)
#pragma unroll
    for (int n = 0; n < FN; n++)
#pragma unroll
      for (int r = 0; r < 4; r++) {
        const int row = m0 + wm + m*16 + l4*4 + r;
        const int col = n0 + wn + n*16 + l15;
        const size_t idx = (size_t)row*N + col;
        const float v = acc[m][n][r];
        if (EPI == 0) ((ushort_t*)Cout)[idx] = f2bf(v);
        else          ((float*)Cout)[(size_t)blockIdx.z*((size_t)M*N) + idx] = v;
      }
}

// ---------------------------------------------------------------------------
// Fused GU+SwiGLU: hmid[2048][4096] = silu(xn@Wg) * (xn@Wu), tile 128x128,
// two B-panels (guT rows [n0,n0+128) gate, [4096+n0,..) up), dual accumulators.
// Measured R9: 40us, 860 TF, 0 bank conflicts.
// ---------------------------------------------------------------------------
__global__ __launch_bounds__(256, 2) void gemm_gu_swiglu(
    const ushort_t* __restrict__ A, const ushort_t* __restrict__ BT,
    ushort_t* __restrict__ H) {
  constexpr int BK = 64;
  __shared__ ushort_t Al[128*BK];
  __shared__ ushort_t Bg[128*BK];
  __shared__ ushort_t Bu[128*BK];
  const int t = threadIdx.x, lane = t & 63;
  const int l15 = lane & 15, l4 = lane >> 4;
  int bid = blockIdx.y * gridDim.x + blockIdx.x;    // 32 x 16 = 512
  const int nwg = gridDim.x * gridDim.y;
  bid = (bid & 7) * (nwg >> 3) + (bid >> 3);        // XCD swizzle (512 % 8 == 0)
  const int n0 = (bid % gridDim.x) * 128;
  const int m0 = (bid / gridDim.x) * 128;
  const int wm = ((t >> 6) >> 1) * 64;
  const int wn = ((t >> 6) & 1) * 64;
  const f32x4 zf = {0.f, 0.f, 0.f, 0.f};
  f32x4 ag[4][4], au[4][4];
#pragma unroll
  for (int m = 0; m < 4; m++)
#pragma unroll
    for (int n = 0; n < 4; n++) { ag[m][n] = zf; au[m][n] = zf; }
  const int sw = l15 & 7;
  for (int k0 = 0; k0 < 1024; k0 += BK) {
#pragma unroll
    for (int i = 0; i < 4; i++) {
      const int c = i*256 + t, row = c >> 3, ch = (c & 7) ^ (row & 7);
      gld16(&A [(size_t)(m0 + row)*1024 + k0 + ch*8], &Al[c*8]);
      gld16(&BT[(size_t)(n0 + row)*1024 + k0 + ch*8], &Bg[c*8]);
      gld16(&BT[(size_t)(4096 + n0 + row)*1024 + k0 + ch*8], &Bu[c*8]);
    }
    __syncthreads();
#pragma unroll
    for (int kc = 0; kc < BK; kc += 32) {
      const int co = (((kc >> 3) + l4) ^ sw)*8;
      bf16x8 af[4], bgf[4], buf_[4];
#pragma unroll
      for (int m = 0; m < 4; m++) af[m]   = *(const bf16x8*)&Al[(wm + m*16 + l15)*BK + co];
#pragma unroll
      for (int n = 0; n < 4; n++) bgf[n]  = *(const bf16x8*)&Bg[(wn + n*16 + l15)*BK + co];
#pragma unroll
      for (int n = 0; n < 4; n++) buf_[n] = *(const bf16x8*)&Bu[(wn + n*16 + l15)*BK + co];
#pragma unroll
      for (int m = 0; m < 4; m++)
#pragma unroll
        for (int n = 0; n < 4; n++) {
          ag[m][n] = __builtin_amdgcn_mfma_f32_16x16x32_bf16(af[m], bgf[n], ag[m][n], 0, 0, 0);
          au[m][n] = __builtin_amdgcn_mfma_f32_16x16x32_bf16(af[m], buf_[n], au[m][n], 0, 0, 0);
        }
    }
    __syncthreads();
  }
#pragma unroll
  for (int m = 0; m < 4; m++)
#pragma unroll
    for (int n = 0; n < 4; n++)
#pragma unroll
      for (int r = 0; r < 4; r++) {
        const int row = m0 + wm + m*16 + l4*4 + r;
        const int col = n0 + wn + n*16 + l15;
        const float g = ag[m][n][r], u = au[m][n][r];
        H[(size_t)row*4096 + col] = f2bf(u * g / (1.0f + __expf(-g)));
      }
}

// ---------------------------------------------------------------------------
// col attention: block = (c,h,b); 32 strided queries x 32 strided keys, fp32 vector
// ---------------------------------------------------------------------------
__global__ __launch_bounds__(256) void attn_col_k(const ushort_t* __restrict__ qkv,
                                                  ushort_t* __restrict__ O) {
  __shared__ float Qs[32][65], Ks[32][65], Vs[32][65], P[32][33];
  const int c = blockIdx.x, h = blockIdx.y, b = blockIdx.z, t = threadIdx.x;
  const size_t base = (size_t)b*1024*3072 + h*64;
  for (int e = t; e < 2048; e += 256) {
    const int u = e >> 6, d = e & 63;
    const size_t rb = base + (size_t)(c + 32*u)*3072 + d;
    Qs[u][d] = bf2f(qkv[rb]);
    Ks[u][d] = bf2f(qkv[rb + 1024]);
    Vs[u][d] = bf2f(qkv[rb + 2048]);
  }
  __syncthreads();
  const int u = t >> 3, kq = (t & 7)*4;
  float sc[4] = {0.f, 0.f, 0.f, 0.f};
  for (int d = 0; d < 64; d++) {
    const float q = Qs[u][d];
#pragma unroll
    for (int j = 0; j < 4; j++) sc[j] += q * Ks[kq + j][d];
  }
#pragma unroll
  for (int j = 0; j < 4; j++) P[u][kq + j] = __expf(sc[j] * 0.125f);
  __syncthreads();
  if (t < 32) {
    float sum = 0.f;
    for (int j = 0; j < 32; j++) sum += P[t][j];
    const float inv = 1.0f / sum;
    for (int j = 0; j < 32; j++) P[t][j] *= inv;
  }
  __syncthreads();
  const int dg = (t & 7)*8;
  float o[8] = {0.f,0.f,0.f,0.f,0.f,0.f,0.f,0.f};
  for (int k = 0; k < 32; k++) {
    const float p = P[u][k];
#pragma unroll
    for (int j = 0; j < 8; j++) o[j] += p * Vs[k][dg + j];
  }
  uint4 w4;
  w4.x = pk2(f2bf(o[0]), f2bf(o[1])); w4.y = pk2(f2bf(o[2]), f2bf(o[3]));
  w4.z = pk2(f2bf(o[4]), f2bf(o[5])); w4.w = pk2(f2bf(o[6]), f2bf(o[7]));
  *(uint4*)&O[(size_t)(b*1024 + c + 32*u)*1024 + h*64 + dg] = w4;
}

// ---------------------------------------------------------------------------
// MFMA flash attention, 64-key tiles, stride-66 LDS, register prefetch (T14),
// NO-MAX softmax (scores bounded by construction; masked -> exp(-1e30)=0).
// MASK: 0=feat(128 block), 1=nbr(band 64), 2=full (NSPLIT k-split, (O,l) partials).
// ---------------------------------------------------------------------------
template<int MASK, int NSPLIT>
__global__ __launch_bounds__(256, 4) void attn_flash_k(const ushort_t* __restrict__ qkv,
    ushort_t* __restrict__ O, float* __restrict__ Opart, float* __restrict__ Lpart) {
  constexpr int LP = 66;   // row stride: LP/2==33 ==1 mod 32 -> <=2-way banks
  __shared__ ushort_t Kl[64*LP];
  __shared__ ushort_t Vt[64*LP];
  __shared__ ushort_t Pl[4][16*LP];
  const int t = threadIdx.x, lane = t & 63, wave = t >> 6;
  const int l15 = lane & 15, l4 = lane >> 4;
  const int qt = blockIdx.x, h = blockIdx.y;
  const int b = blockIdx.z / NSPLIT, sp = blockIdx.z % NSPLIT;
  const int q0 = qt*64;
  const size_t base = (size_t)b*1024*3072 + h*64;
  const int qrow = q0 + wave*16 + l15;
  const bf16x8 qf0 = *(const bf16x8*)&qkv[base + (size_t)qrow*3072 + l4*8];
  const bf16x8 qf1 = *(const bf16x8*)&qkv[base + (size_t)qrow*3072 + 32 + l4*8];
  int klo, khi;
  if (MASK == 0)      { klo = q0 & ~127; khi = klo + 128; }
  else if (MASK == 1) { klo = (q0 >= 64) ? q0 - 64 : 0; khi = (q0 + 128 < 1024) ? q0 + 128 : 1024; }
  else                { klo = sp * (1024/NSPLIT); khi = klo + 1024/NSPLIT; }
  const int kr = t >> 2, kd = (t & 3)*16;             // K staging coords
  const int vk2 = (t & 31)*2, vd = (t >> 5)*8;        // V staging coords (2 rows x 8 d)
  const ushort_t* kptr = qkv + base + 1024 + (size_t)kr*3072 + kd;
  const ushort_t* vptr = qkv + base + 2048 + (size_t)vk2*3072 + vd;
  bf16x8 kg0 = *(const bf16x8*)&kptr[(size_t)klo*3072];
  bf16x8 kg1 = *(const bf16x8*)&kptr[(size_t)klo*3072 + 8];
  bf16x8 vg0 = *(const bf16x8*)&vptr[(size_t)klo*3072];
  bf16x8 vg1 = *(const bf16x8*)&vptr[(size_t)klo*3072 + 3072];
  const f32x4 zf = {0.f, 0.f, 0.f, 0.f};
  f32x4 of[4];
#pragma unroll
  for (int n = 0; n < 4; n++) of[n] = zf;
  float lrow[4] = {0.f, 0.f, 0.f, 0.f};

  for (int kb = klo; kb < khi; kb += 64) {
    *(bf16x8*)&Kl[kr*LP + kd] = kg0;
    *(bf16x8*)&Kl[kr*LP + kd + 8] = kg1;
#pragma unroll
    for (int j = 0; j < 8; j++)   // Vt[d][k]=V[k][d]: packed pair of k-rows
      *(uint_t*)&Vt[(vd + j)*LP + vk2] = pk2((ushort_t)vg0[j], (ushort_t)vg1[j]);
    __syncthreads();
    if (kb + 64 < khi) {   // T14: prefetch next tile into regs
      kg0 = *(const bf16x8*)&kptr[(size_t)(kb+64)*3072];
      kg1 = *(const bf16x8*)&kptr[(size_t)(kb+64)*3072 + 8];
      vg0 = *(const bf16x8*)&vptr[(size_t)(kb+64)*3072];
      vg1 = *(const bf16x8*)&vptr[(size_t)(kb+64)*3072 + 3072];
    }
    f32x4 sf[4];
    __builtin_amdgcn_s_setprio(1);
#pragma unroll
    for (int s = 0; s < 4; s++) {
      const bf16x8 k0 = *(const bf16x8*)&Kl[(s*16 + l15)*LP + l4*8];
      const bf16x8 k1 = *(const bf16x8*)&Kl[(s*16 + l15)*LP + 32 + l4*8];
      sf[s] = __builtin_amdgcn_mfma_f32_16x16x32_bf16(qf0, k0, zf, 0, 0, 0);
      sf[s] = __builtin_amdgcn_mfma_f32_16x16x32_bf16(qf1, k1, sf[s], 0, 0, 0);
    }
    __builtin_amdgcn_s_setprio(0);
    // no-max softmax: p = exp(s/8); masked s -> -1e30 -> p = 0
    float psum[4] = {0.f, 0.f, 0.f, 0.f};
#pragma unroll
    for (int s = 0; s < 4; s++)
#pragma unroll
      for (int r = 0; r < 4; r++) {
        float a = sf[s][r]*0.125f;
        if (MASK == 1) {
          const int d = (q0 + wave*16 + l4*4 + r) - (kb + s*16 + l15);
          if (d > 64 || d < -64) a = -1e30f;
        }
        const float p = __expf(a);
        psum[r] += p;
        Pl[wave][(l4*4 + r)*LP + s*16 + l15] = f2bf(p);
      }
#pragma unroll
    for (int mk = 1; mk < 16; mk <<= 1)
#pragma unroll
      for (int r = 0; r < 4; r++) psum[r] += __shfl_xor(psum[r], mk);
#pragma unroll
    for (int r = 0; r < 4; r++) lrow[r] += psum[r];
    const bf16x8 pa0 = *(const bf16x8*)&Pl[wave][l15*LP + l4*8];
    const bf16x8 pa1 = *(const bf16x8*)&Pl[wave][l15*LP + 32 + l4*8];
    __builtin_amdgcn_s_setprio(1);
#pragma unroll
    for (int n = 0; n < 4; n++) {
      const bf16x8 v0 = *(const bf16x8*)&Vt[(n*16 + l15)*LP + l4*8];
      const bf16x8 v1 = *(const bf16x8*)&Vt[(n*16 + l15)*LP + 32 + l4*8];
      of[n] = __builtin_amdgcn_mfma_f32_16x16x32_bf16(pa0, v0, of[n], 0, 0, 0);
      of[n] = __builtin_amdgcn_mfma_f32_16x16x32_bf16(pa1, v1, of[n], 0, 0, 0);
    }
    __builtin_amdgcn_s_setprio(0);
    __syncthreads();
  }
  if (NSPLIT == 1) {
#pragma unroll
    for (int n = 0; n < 4; n++)
#pragma unroll
      for (int r = 0; r < 4; r++) {
        const int qg = q0 + wave*16 + l4*4 + r;
        O[(size_t)(b*1024 + qg)*1024 + h*64 + n*16 + l15] = f2bf(of[n][r] / lrow[r]);
      }
  } else {
#pragma unroll
    for (int r = 0; r < 4; r++) {
      const int qg = q0 + wave*16 + l4*4 + r;
      const size_t row = ((size_t)(sp*2 + b)*1024 + qg)*16 + h;
#pragma unroll
      for (int n = 0; n < 4; n++) Opart[row*64 + n*16 + l15] = of[n][r];
      if (l15 == 0) Lpart[row] = lrow[r];
    }
  }
}

// merge NS k-splits (no-max): O = sum_s O_s / sum_s l_s
template<int NS>
__global__ __launch_bounds__(256) void attn_merge_k(const float* __restrict__ Opart,
    const float* __restrict__ L, ushort_t* __restrict__ O) {
  const int idx = blockIdx.x*256 + threadIdx.x;   // 2*1024*16*8 threads
  const int d8 = (idx & 7)*8;
  const int h  = (idx >> 3) & 15;
  const int q  = (idx >> 7) & 1023;
  const int b  = idx >> 17;
  float den = 0.f;
  float acc[8] = {0,0,0,0,0,0,0,0};
#pragma unroll
  for (int s = 0; s < NS; s++) {
    const size_t row = ((size_t)(s*2 + b)*1024 + q)*16 + h;
    den += L[row];
    const float4* op = (const float4*)&Opart[row*64 + d8];
    const float4 a = op[0], c = op[1];
    acc[0] += a.x; acc[1] += a.y; acc[2] += a.z; acc[3] += a.w;
    acc[4] += c.x; acc[5] += c.y; acc[6] += c.z; acc[7] += c.w;
  }
  const float inv = 1.0f / den;
  uint4 w4;
  w4.x = pk2(f2bf(acc[0]*inv), f2bf(acc[1]*inv));
  w4.y = pk2(f2bf(acc[2]*inv), f2bf(acc[3]*inv));
  w4.z = pk2(f2bf(acc[4]*inv), f2bf(acc[5]*inv));
  w4.w = pk2(f2bf(acc[6]*inv), f2bf(acc[7]*inv));
  *(uint4*)&O[((size_t)b*1024 + q)*1024 + h*64 + d8] = w4;
}

// ---------------------------------------------------------------------------
extern "C" void kernel_launch(void* const* d_in, const int* in_sizes, int n_in,
                              void* d_out, int out_size, void* d_ws, size_t ws_size,
                              hipStream_t stream) {
  (void)in_sizes; (void)n_in; (void)out_size; (void)ws_size;
  const float* x_in = (const float*)d_in[0];
  const float* norm[5] = { (const float*)d_in[5], (const float*)d_in[10], (const float*)d_in[15],
                           (const float*)d_in[20], (const float*)d_in[25] };
  char* w = (char*)d_ws;
  auto alloc = [&](size_t bytes) { char* p = w; w += (bytes + 255) & ~(size_t)255; return p; };
  ushort_t* qkvT = (ushort_t*)alloc(4ull*3072*1024*2);
  ushort_t* woT  = (ushort_t*)alloc(4ull*1024*1024*2);
  ushort_t* guT  = (ushort_t*)alloc(8192ull*1024*2);
  ushort_t* dnT  = (ushort_t*)alloc(4096ull*1024*2);
  float*    xbuf = (float*)  alloc(2048ull*1024*4);
  ushort_t* xn   = (ushort_t*)alloc(2048ull*1024*2);
  ushort_t* qkv  = (ushort_t*)alloc(2048ull*3072*2);
  ushort_t* attO = (ushort_t*)alloc(2048ull*1024*2);
  ushort_t* hmid = (ushort_t*)alloc(2048ull*4096*2);
  float*  scratch = (float*)alloc(8ull*1024*16*64*4);   // 33.5MB: Pp / Opart (disjoint lifetimes)
  float* Pp    = scratch;        // split-K partials: up to 2 x 8.4MB
  float* Opart = scratch;        // full-attn O partials (4 x 8.4MB)
  float* Lpart = (float*)hmid;   // full-attn l partials (hmid written later, in FFN)

  TPtrs tp;
  for (int l = 0; l < 4; l++) {
    tp.src[l*4 + 0] = (const float*)d_in[6 + l*5];
    tp.src[l*4 + 1] = (const float*)d_in[7 + l*5];
    tp.src[l*4 + 2] = (const float*)d_in[8 + l*5];
    tp.src[l*4 + 3] = (const float*)d_in[9 + l*5];
  }
  tp.src[16] = (const float*)d_in[27];   // w_gate
  tp.src[17] = (const float*)d_in[26];   // w_up
  tp.src[18] = (const float*)d_in[28];   // w_down
  transpose_all<<<28672, 256, 0, stream>>>(tp, qkvT, woT, guT, dnT);

  // prologue: xbuf = x_in, xn = rms(x_in)*norm0
  fused_add_rms<0,1><<<2048, 256, 0, stream>>>(x_in, nullptr, norm[0], xbuf, xn);

  for (int l = 0; l < 4; l++) {
    // QKV: 128x96 tile, grid (32,16)=512 blocks
    gemm_bt<128,96,0,1><<<dim3(3072/96, 2048/128), 256, 0, stream>>>(
        xn, qkvT + (size_t)l*3072*1024, qkv, 2048, 3072, 1024);
    if (l == 0)      attn_col_k         <<<dim3(32, 16, 2), 256, 0, stream>>>(qkv, attO);
    else if (l == 1) attn_flash_k<0,1>  <<<dim3(16, 16, 2), 256, 0, stream>>>(qkv, attO, nullptr, nullptr);
    else if (l == 2) attn_flash_k<1,1>  <<<dim3(16, 16, 2), 256, 0, stream>>>(qkv, attO, nullptr, nullptr);
    else {
      attn_flash_k<2,4><<<dim3(16, 16, 8), 256, 0, stream>>>(qkv, nullptr, Opart, Lpart);
      attn_merge_k<4><<<1024, 256, 0, stream>>>(Opart, Lpart, attO);
    }
    // WO: 128x64 SK2 partials (512 blocks), then fused residual+next-rms
    gemm_bt<128,64,3,2><<<dim3(1024/64, 2048/128, 2), 256, 0, stream>>>(
        attO, woT + (size_t)l*1024*1024, Pp, 2048, 1024, 1024);
    fused_add_rms<2,1><<<2048, 256, 0, stream>>>(xbuf, Pp, norm[l+1 < 4 ? l+1 : 4], xbuf, xn);
  }
  // FFN: fused GU+SwiGLU -> hmid, then down-proj SK2 + fused residual
  gemm_gu_swiglu<<<dim3(4096/128, 2048/128), 256, 0, stream>>>(xn, guT, hmid);
  gemm_bt<128,64,3,2><<<dim3(1024/64, 2048/128, 2), 256, 0, stream>>>(
      hmid, dnT, Pp, 2048, 1024, 4096);
  fused_add_rms<2,0><<<2048, 256, 0, stream>>>(xbuf, Pp, nullptr, (float*)d_out, nullptr);
}

// Round 12
// 502.524 us; speedup vs baseline: 1.0088x; 1.0088x over previous
//
#include <hip/hip_runtime.h>
#include <math.h>
#include <stdint.h>

// ============================================================================
// RelationalBlock: 4x (rmsnorm -> attn(mask) -> +res) -> rmsnorm -> SwiGLU -> +res
// B=2 S=1024 D=1024 H=16 hd=64 DFF=4096. All GEMMs bf16-MFMA (fp32 accum).
// Masks index-structured: L0 col j%32==i%32, L1 feat j/128==i/128,
//   L2 nbr |i-j|<=64, L3 full.
// R11 fix: transpose_all was the longest kernel (55us @ 2.1 TB/s) -- scalar
//   4B loads / 2B stores were request-bound. -> 64x64 tiles, float4 reads
//   (256B segments), XOR-swizzled fp32 LDS (col ^= row&60, 2-way banks, self
//   inverse), ushort4 writes (128B segments). Everything else unchanged from
//   the measured 507us kernel (down SK2, QKV 128x96, fused GU+SwiGLU etc).
// ============================================================================

typedef __attribute__((ext_vector_type(8))) short bf16x8;
typedef __attribute__((ext_vector_type(4))) float f32x4;
typedef unsigned short ushort_t;
typedef unsigned int uint_t;

#define DEV static __device__ __forceinline__

DEV float bf2f(ushort_t u) { union { uint_t i; float f; } v; v.i = ((uint_t)u) << 16; return v.f; }
DEV ushort_t f2bf(float f) {             // round-to-nearest-even bf16
  union { float f; uint_t i; } v; v.f = f;
  uint_t r = v.i + 0x7fffu + ((v.i >> 16) & 1u);
  return (ushort_t)(r >> 16);
}
DEV uint_t pk2(ushort_t a, ushort_t b) { return (uint_t)a | ((uint_t)b << 16); }

DEV void gld16(const ushort_t* g, ushort_t* l) {   // async global->LDS, 16B/lane
  __builtin_amdgcn_global_load_lds((const __attribute__((address_space(1))) void*)g,
                                   (__attribute__((address_space(3))) void*)l, 16, 0, 0);
}

// ---------------------------------------------------------------------------
// All weight transposes in ONE kernel, 64x64 tiles, vectorized.
// fp32 [R][C] -> bf16 [C][R]. Segments: [0,4096) qkv/wo (16 mats x 256 tiles);
// [4096,6144) gate/up (2 x 1024); [6144,7168) down (1024).
// LDS: fp32 [64][64], col XOR-swizzled by (row & 60): 2-way banks both
// phases, self-inverse, 16B-alignment preserved (XOR acts on bits >= 2).
// ---------------------------------------------------------------------------
struct TPtrs { const float* src[19]; };   // 0..15 qkv/wo, 16 gate, 17 up, 18 down

__global__ __launch_bounds__(256) void transpose_all(TPtrs P, ushort_t* __restrict__ qkvT,
    ushort_t* __restrict__ woT, ushort_t* __restrict__ guT, ushort_t* __restrict__ dnT) {
  __shared__ float tile[64*64];
  const int bid = blockIdx.x, t = threadIdx.x;
  const float* src; ushort_t* dst; int C, R, bx, by;
  if (bid < 4096) {
    const int mz = bid >> 8, i = bid & 255;
    bx = i & 15; by = i >> 4;
    src = P.src[mz]; R = 1024; C = 1024;
    const int l = mz >> 2, which = mz & 3;
    dst = (which < 3) ? (qkvT + (size_t)l*3072*1024 + (size_t)which*1024*1024)
                      : (woT  + (size_t)l*1024*1024);
  } else if (bid < 6144) {
    const int seg = (bid - 4096) >> 10, i = (bid - 4096) & 1023;
    bx = i & 63; by = i >> 6;
    src = P.src[16 + seg]; R = 1024; C = 4096;
    dst = guT + (size_t)seg*4096*1024;
  } else {
    const int i = bid - 6144;
    bx = i & 15; by = i >> 4;
    src = P.src[18]; R = 4096; C = 1024;
    dst = dnT;
  }
  const int r0 = by*64, c0 = bx*64;
  // load: float4 per thread x4 iters; LDS col-swizzled
#pragma unroll
  for (int i = 0; i < 4; i++) {
    const int idx = i*256 + t;
    const int r = idx >> 4, c4 = (idx & 15) << 2;
    const float4 v = *(const float4*)&src[(size_t)(r0 + r)*C + c0 + c4];
    *(float4*)&tile[r*64 + (c4 ^ (r & 60))] = v;
  }
  __syncthreads();
  // store: 4 scalar LDS reads -> ushort4 global write
#pragma unroll
  for (int i = 0; i < 4; i++) {
    const int idx = i*256 + t;
    const int orow = idx >> 4, r4 = (idx & 15) << 2;   // orow = src col, r4 = src row base
    ushort_t o[4];
#pragma unroll
    for (int j = 0; j < 4; j++) {
      const int rr = r4 + j;
      o[j] = f2bf(tile[rr*64 + (((orow & ~3) ^ (rr & 60)) | (orow & 3))]);
    }
    uint2 w2;
    w2.x = pk2(o[0], o[1]); w2.y = pk2(o[2], o[3]);
    *(uint2*)&dst[(size_t)(c0 + orow)*R + r0 + r4] = w2;
  }
}

// ---------------------------------------------------------------------------
// fused: x = resid + sum_s Pp[s]; write x (fp32); optionally xn = rms(x)*w (bf16)
// ---------------------------------------------------------------------------
template<int NS, int RMS>
__global__ __launch_bounds__(256) void fused_add_rms(
    const float* __restrict__ resid, const float* __restrict__ Pp,
    const float* __restrict__ w, float* __restrict__ xout,
    ushort_t* __restrict__ xn) {
  const int row = blockIdx.x, t = threadIdx.x;
  const size_t off = (size_t)row*1024 + t*4;
  float4 v = *(const float4*)&resid[off];
#pragma unroll
  for (int s = 0; s < NS; s++) {
    const float4 p = *(const float4*)&Pp[(size_t)s*(2048ull*1024) + off];
    v.x += p.x; v.y += p.y; v.z += p.z; v.w += p.w;
  }
  *(float4*)&xout[off] = v;
  if (RMS) {
    float ss = v.x*v.x + v.y*v.y + v.z*v.z + v.w*v.w;
#pragma unroll
    for (int m = 32; m; m >>= 1) ss += __shfl_xor(ss, m);
    __shared__ float red[4];
    if ((t & 63) == 0) red[t >> 6] = ss;
    __syncthreads();
    const float tot = red[0] + red[1] + red[2] + red[3];
    const float rs = rsqrtf(tot * (1.0f/1024.0f) + 1.1920929e-07f);
    const float4 wv = ((const float4*)w)[t];
    uint2 o;
    o.x = pk2(f2bf(v.x*rs*wv.x), f2bf(v.y*rs*wv.y));
    o.y = pk2(f2bf(v.z*rs*wv.z), f2bf(v.w*rs*wv.w));
    *(uint2*)&xn[off] = o;
  }
}

// ---------------------------------------------------------------------------
// GEMM: C[M][N] (+)= A[M][K](bf16) * BT[N][K](bf16)^T. m97 structure + XOR
// chunk swizzle (conflict-free ds_read; source pre-swizzled, LDS linear).
// EPI 0: bf16 store (SPLITK==1). EPI 3: fp32 partial store to slot blockIdx.z.
// Invariant for swizzle: BM/2, BN/2 multiples of 8 (row&7 == l15&7).
// ---------------------------------------------------------------------------
template<int BM, int BN, int EPI, int SPLITK>
__global__ __launch_bounds__(256, 4) void gemm_bt(
    const ushort_t* __restrict__ A, const ushort_t* __restrict__ BT,
    void* __restrict__ Cout, int M, int N, int K) {
  constexpr int BK = 64;
  __shared__ ushort_t Al[BM*BK];
  __shared__ ushort_t Bl[BN*BK];
  const int t = threadIdx.x, lane = t & 63;
  const int l15 = lane & 15, l4 = lane >> 4;
  int bid = blockIdx.y * gridDim.x + blockIdx.x;
  const int nwg = gridDim.x * gridDim.y;
  if ((nwg & 7) == 0) bid = (bid & 7) * (nwg >> 3) + (bid >> 3);
  const int n0 = (bid % gridDim.x) * BN;
  const int m0 = (bid / gridDim.x) * BM;
  constexpr int WM = BM/2, WN = BN/2, FM = WM/16, FN = WN/16;
  const int wm = ((t >> 6) >> 1) * WM;
  const int wn = ((t >> 6) & 1) * WN;
  const f32x4 zf = {0.f, 0.f, 0.f, 0.f};
  f32x4 acc[FM][FN];
#pragma unroll
  for (int m = 0; m < FM; m++)
#pragma unroll
    for (int n = 0; n < FN; n++) acc[m][n] = zf;
  constexpr int CA = (BM*BK)/(256*8), CB = (BN*BK)/(256*8);
  const int kz = blockIdx.z * (K / SPLITK);
  const int sw = l15 & 7;   // read-side XOR key
  for (int k0 = kz; k0 < kz + K / SPLITK; k0 += BK) {
#pragma unroll
    for (int i = 0; i < CA; i++) {
      const int c = i*256 + t, row = c >> 3, ch = (c & 7) ^ (row & 7);
      gld16(&A[(size_t)(m0 + row)*K + k0 + ch*8], &Al[c*8]);
    }
#pragma unroll
    for (int i = 0; i < CB; i++) {
      const int c = i*256 + t, row = c >> 3, ch = (c & 7) ^ (row & 7);
      gld16(&BT[(size_t)(n0 + row)*K + k0 + ch*8], &Bl[c*8]);
    }
    __syncthreads();
#pragma unroll
    for (int kc = 0; kc < BK; kc += 32) {
      bf16x8 af[FM], bfr[FN];
#pragma unroll
      for (int m = 0; m < FM; m++)
        af[m] = *(const bf16x8*)&Al[(wm + m*16 + l15)*BK + (((kc >> 3) + l4) ^ sw)*8];
#pragma unroll
      for (int n = 0; n < FN; n++)
        bfr[n] = *(const bf16x8*)&Bl[(wn + n*16 + l15)*BK + (((kc >> 3) + l4) ^ sw)*8];
#pragma unroll
      for (int m = 0; m < FM; m++)
#pragma unroll
        for (int n = 0; n < FN; n++)
          acc[m][n] = __builtin_amdgcn_mfma_f32_16x16x32_bf16(af[m], bfr[n], acc[m][n], 0, 0, 0);
    }
    __syncthreads();
  }
#pragma unroll
  for (int m = 0; m < FM; m++)
#pragma unroll
    for (int n = 0; n < FN; n++)
#pragma unroll
      for (int r = 0; r < 4; r++) {
        const int row = m0 + wm + m*16 + l4*4 + r;
        const int col = n0 + wn + n*16 + l15;
        const size_t idx = (size_t)row*N + col;
        const float v = acc[m][n][r];
        if (EPI == 0) ((ushort_t*)Cout)[idx] = f2bf(v);
        else          ((float*)Cout)[(size_t)blockIdx.z*((size_t)M*N) + idx] = v;
      }
}

// ---------------------------------------------------------------------------
// Fused GU+SwiGLU: hmid[2048][4096] = silu(xn@Wg) * (xn@Wu), tile 128x128,
// two B-panels (guT rows [n0,n0+128) gate, [4096+n0,..) up), dual accumulators.
// Measured R9: 40us, 860 TF, 0 bank conflicts.
// ---------------------------------------------------------------------------
__global__ __launch_bounds__(256, 2) void gemm_gu_swiglu(
    const ushort_t* __restrict__ A, const ushort_t* __restrict__ BT,
    ushort_t* __restrict__ H) {
  constexpr int BK = 64;
  __shared__ ushort_t Al[128*BK];
  __shared__ ushort_t Bg[128*BK];
  __shared__ ushort_t Bu[128*BK];
  const int t = threadIdx.x, lane = t & 63;
  const int l15 = lane & 15, l4 = lane >> 4;
  int bid = blockIdx.y * gridDim.x + blockIdx.x;    // 32 x 16 = 512
  const int nwg = gridDim.x * gridDim.y;
  bid = (bid & 7) * (nwg >> 3) + (bid >> 3);        // XCD swizzle (512 % 8 == 0)
  const int n0 = (bid % gridDim.x) * 128;
  const int m0 = (bid / gridDim.x) * 128;
  const int wm = ((t >> 6) >> 1) * 64;
  const int wn = ((t >> 6) & 1) * 64;
  const f32x4 zf = {0.f, 0.f, 0.f, 0.f};
  f32x4 ag[4][4], au[4][4];
#pragma unroll
  for (int m = 0; m < 4; m++)
#pragma unroll
    for (int n = 0; n < 4; n++) { ag[m][n] = zf; au[m][n] = zf; }
  const int sw = l15 & 7;
  for (int k0 = 0; k0 < 1024; k0 += BK) {
#pragma unroll
    for (int i = 0; i < 4; i++) {
      const int c = i*256 + t, row = c >> 3, ch = (c & 7) ^ (row & 7);
      gld16(&A [(size_t)(m0 + row)*1024 + k0 + ch*8], &Al[c*8]);
      gld16(&BT[(size_t)(n0 + row)*1024 + k0 + ch*8], &Bg[c*8]);
      gld16(&BT[(size_t)(4096 + n0 + row)*1024 + k0 + ch*8], &Bu[c*8]);
    }
    __syncthreads();
#pragma unroll
    for (int kc = 0; kc < BK; kc += 32) {
      const int co = (((kc >> 3) + l4) ^ sw)*8;
      bf16x8 af[4], bgf[4], buf_[4];
#pragma unroll
      for (int m = 0; m < 4; m++) af[m]   = *(const bf16x8*)&Al[(wm + m*16 + l15)*BK + co];
#pragma unroll
      for (int n = 0; n < 4; n++) bgf[n]  = *(const bf16x8*)&Bg[(wn + n*16 + l15)*BK + co];
#pragma unroll
      for (int n = 0; n < 4; n++) buf_[n] = *(const bf16x8*)&Bu[(wn + n*16 + l15)*BK + co];
#pragma unroll
      for (int m = 0; m < 4; m++)
#pragma unroll
        for (int n = 0; n < 4; n++) {
          ag[m][n] = __builtin_amdgcn_mfma_f32_16x16x32_bf16(af[m], bgf[n], ag[m][n], 0, 0, 0);
          au[m][n] = __builtin_amdgcn_mfma_f32_16x16x32_bf16(af[m], buf_[n], au[m][n], 0, 0, 0);
        }
    }
    __syncthreads();
  }
#pragma unroll
  for (int m = 0; m < 4; m++)
#pragma unroll
    for (int n = 0; n < 4; n++)
#pragma unroll
      for (int r = 0; r < 4; r++) {
        const int row = m0 + wm + m*16 + l4*4 + r;
        const int col = n0 + wn + n*16 + l15;
        const float g = ag[m][n][r], u = au[m][n][r];
        H[(size_t)row*4096 + col] = f2bf(u * g / (1.0f + __expf(-g)));
      }
}

// ---------------------------------------------------------------------------
// col attention: block = (c,h,b); 32 strided queries x 32 strided keys, fp32 vector
// ---------------------------------------------------------------------------
__global__ __launch_bounds__(256) void attn_col_k(const ushort_t* __restrict__ qkv,
                                                  ushort_t* __restrict__ O) {
  __shared__ float Qs[32][65], Ks[32][65], Vs[32][65], P[32][33];
  const int c = blockIdx.x, h = blockIdx.y, b = blockIdx.z, t = threadIdx.x;
  const size_t base = (size_t)b*1024*3072 + h*64;
  for (int e = t; e < 2048; e += 256) {
    const int u = e >> 6, d = e & 63;
    const size_t rb = base + (size_t)(c + 32*u)*3072 + d;
    Qs[u][d] = bf2f(qkv[rb]);
    Ks[u][d] = bf2f(qkv[rb + 1024]);
    Vs[u][d] = bf2f(qkv[rb + 2048]);
  }
  __syncthreads();
  const int u = t >> 3, kq = (t & 7)*4;
  float sc[4] = {0.f, 0.f, 0.f, 0.f};
  for (int d = 0; d < 64; d++) {
    const float q = Qs[u][d];
#pragma unroll
    for (int j = 0; j < 4; j++) sc[j] += q * Ks[kq + j][d];
  }
#pragma unroll
  for (int j = 0; j < 4; j++) P[u][kq + j] = __expf(sc[j] * 0.125f);
  __syncthreads();
  if (t < 32) {
    float sum = 0.f;
    for (int j = 0; j < 32; j++) sum += P[t][j];
    const float inv = 1.0f / sum;
    for (int j = 0; j < 32; j++) P[t][j] *= inv;
  }
  __syncthreads();
  const int dg = (t & 7)*8;
  float o[8] = {0.f,0.f,0.f,0.f,0.f,0.f,0.f,0.f};
  for (int k = 0; k < 32; k++) {
    const float p = P[u][k];
#pragma unroll
    for (int j = 0; j < 8; j++) o[j] += p * Vs[k][dg + j];
  }
  uint4 w4;
  w4.x = pk2(f2bf(o[0]), f2bf(o[1])); w4.y = pk2(f2bf(o[2]), f2bf(o[3]));
  w4.z = pk2(f2bf(o[4]), f2bf(o[5])); w4.w = pk2(f2bf(o[6]), f2bf(o[7]));
  *(uint4*)&O[(size_t)(b*1024 + c + 32*u)*1024 + h*64 + dg] = w4;
}

// ---------------------------------------------------------------------------
// MFMA flash attention, 64-key tiles, stride-66 LDS, register prefetch (T14),
// NO-MAX softmax (scores bounded by construction; masked -> exp(-1e30)=0).
// MASK: 0=feat(128 block), 1=nbr(band 64), 2=full (NSPLIT k-split, (O,l) partials).
// ---------------------------------------------------------------------------
template<int MASK, int NSPLIT>
__global__ __launch_bounds__(256, 4) void attn_flash_k(const ushort_t* __restrict__ qkv,
    ushort_t* __restrict__ O, float* __restrict__ Opart, float* __restrict__ Lpart) {
  constexpr int LP = 66;   // row stride: LP/2==33 ==1 mod 32 -> <=2-way banks
  __shared__ ushort_t Kl[64*LP];
  __shared__ ushort_t Vt[64*LP];
  __shared__ ushort_t Pl[4][16*LP];
  const int t = threadIdx.x, lane = t & 63, wave = t >> 6;
  const int l15 = lane & 15, l4 = lane >> 4;
  const int qt = blockIdx.x, h = blockIdx.y;
  const int b = blockIdx.z / NSPLIT, sp = blockIdx.z % NSPLIT;
  const int q0 = qt*64;
  const size_t base = (size_t)b*1024*3072 + h*64;
  const int qrow = q0 + wave*16 + l15;
  const bf16x8 qf0 = *(const bf16x8*)&qkv[base + (size_t)qrow*3072 + l4*8];
  const bf16x8 qf1 = *(const bf16x8*)&qkv[base + (size_t)qrow*3072 + 32 + l4*8];
  int klo, khi;
  if (MASK == 0)      { klo = q0 & ~127; khi = klo + 128; }
  else if (MASK == 1) { klo = (q0 >= 64) ? q0 - 64 : 0; khi = (q0 + 128 < 1024) ? q0 + 128 : 1024; }
  else                { klo = sp * (1024/NSPLIT); khi = klo + 1024/NSPLIT; }
  const int kr = t >> 2, kd = (t & 3)*16;             // K staging coords
  const int vk2 = (t & 31)*2, vd = (t >> 5)*8;        // V staging coords (2 rows x 8 d)
  const ushort_t* kptr = qkv + base + 1024 + (size_t)kr*3072 + kd;
  const ushort_t* vptr = qkv + base + 2048 + (size_t)vk2*3072 + vd;
  bf16x8 kg0 = *(const bf16x8*)&kptr[(size_t)klo*3072];
  bf16x8 kg1 = *(const bf16x8*)&kptr[(size_t)klo*3072 + 8];
  bf16x8 vg0 = *(const bf16x8*)&vptr[(size_t)klo*3072];
  bf16x8 vg1 = *(const bf16x8*)&vptr[(size_t)klo*3072 + 3072];
  const f32x4 zf = {0.f, 0.f, 0.f, 0.f};
  f32x4 of[4];
#pragma unroll
  for (int n = 0; n < 4; n++) of[n] = zf;
  float lrow[4] = {0.f, 0.f, 0.f, 0.f};

  for (int kb = klo; kb < khi; kb += 64) {
    *(bf16x8*)&Kl[kr*LP + kd] = kg0;
    *(bf16x8*)&Kl[kr*LP + kd + 8] = kg1;
#pragma unroll
    for (int j = 0; j < 8; j++)   // Vt[d][k]=V[k][d]: packed pair of k-rows
      *(uint_t*)&Vt[(vd + j)*LP + vk2] = pk2((ushort_t)vg0[j], (ushort_t)vg1[j]);
    __syncthreads();
    if (kb + 64 < khi) {   // T14: prefetch next tile into regs
      kg0 = *(const bf16x8*)&kptr[(size_t)(kb+64)*3072];
      kg1 = *(const bf16x8*)&kptr[(size_t)(kb+64)*3072 + 8];
      vg0 = *(const bf16x8*)&vptr[(size_t)(kb+64)*3072];
      vg1 = *(const bf16x8*)&vptr[(size_t)(kb+64)*3072 + 3072];
    }
    f32x4 sf[4];
    __builtin_amdgcn_s_setprio(1);
#pragma unroll
    for (int s = 0; s < 4; s++) {
      const bf16x8 k0 = *(const bf16x8*)&Kl[(s*16 + l15)*LP + l4*8];
      const bf16x8 k1 = *(const bf16x8*)&Kl[(s*16 + l15)*LP + 32 + l4*8];
      sf[s] = __builtin_amdgcn_mfma_f32_16x16x32_bf16(qf0, k0, zf, 0, 0, 0);
      sf[s] = __builtin_amdgcn_mfma_f32_16x16x32_bf16(qf1, k1, sf[s], 0, 0, 0);
    }
    __builtin_amdgcn_s_setprio(0);
    // no-max softmax: p = exp(s/8); masked s -> -1e30 -> p = 0
    float psum[4] = {0.f, 0.f, 0.f, 0.f};
#pragma unroll
    for (int s = 0; s < 4; s++)
#pragma unroll
      for (int r = 0; r < 4; r++) {
        float a = sf[s][r]*0.125f;
        if (MASK == 1) {
          const int d = (q0 + wave*16 + l4*4 + r) - (kb + s*16 + l15);
          if (d > 64 || d < -64) a = -1e30f;
        }
        const float p = __expf(a);
        psum[r] += p;
        Pl[wave][(l4*4 + r)*LP + s*16 + l15] = f2bf(p);
      }
#pragma unroll
    for (int mk = 1; mk < 16; mk <<= 1)
#pragma unroll
      for (int r = 0; r < 4; r++) psum[r] += __shfl_xor(psum[r], mk);
#pragma unroll
    for (int r = 0; r < 4; r++) lrow[r] += psum[r];
    const bf16x8 pa0 = *(const bf16x8*)&Pl[wave][l15*LP + l4*8];
    const bf16x8 pa1 = *(const bf16x8*)&Pl[wave][l15*LP + 32 + l4*8];
    __builtin_amdgcn_s_setprio(1);
#pragma unroll
    for (int n = 0; n < 4; n++) {
      const bf16x8 v0 = *(const bf16x8*)&Vt[(n*16 + l15)*LP + l4*8];
      const bf16x8 v1 = *(const bf16x8*)&Vt[(n*16 + l15)*LP + 32 + l4*8];
      of[n] = __builtin_amdgcn_mfma_f32_16x16x32_bf16(pa0, v0, of[n], 0, 0, 0);
      of[n] = __builtin_amdgcn_mfma_f32_16x16x32_bf16(pa1, v1, of[n], 0, 0, 0);
    }
    __builtin_amdgcn_s_setprio(0);
    __syncthreads();
  }
  if (NSPLIT == 1) {
#pragma unroll
    for (int n = 0; n < 4; n++)
#pragma unroll
      for (int r = 0; r < 4; r++) {
        const int qg = q0 + wave*16 + l4*4 + r;
        O[(size_t)(b*1024 + qg)*1024 + h*64 + n*16 + l15] = f2bf(of[n][r] / lrow[r]);
      }
  } else {
#pragma unroll
    for (int r = 0; r < 4; r++) {
      const int qg = q0 + wave*16 + l4*4 + r;
      const size_t row = ((size_t)(sp*2 + b)*1024 + qg)*16 + h;
#pragma unroll
      for (int n = 0; n < 4; n++) Opart[row*64 + n*16 + l15] = of[n][r];
      if (l15 == 0) Lpart[row] = lrow[r];
    }
  }
}

// merge NS k-splits (no-max): O = sum_s O_s / sum_s l_s
template<int NS>
__global__ __launch_bounds__(256) void attn_merge_k(const float* __restrict__ Opart,
    const float* __restrict__ L, ushort_t* __restrict__ O) {
  const int idx = blockIdx.x*256 + threadIdx.x;   // 2*1024*16*8 threads
  const int d8 = (idx & 7)*8;
  const int h  = (idx >> 3) & 15;
  const int q  = (idx >> 7) & 1023;
  const int b  = idx >> 17;
  float den = 0.f;
  float acc[8] = {0,0,0,0,0,0,0,0};
#pragma unroll
  for (int s = 0; s < NS; s++) {
    const size_t row = ((size_t)(s*2 + b)*1024 + q)*16 + h;
    den += L[row];
    const float4* op = (const float4*)&Opart[row*64 + d8];
    const float4 a = op[0], c = op[1];
    acc[0] += a.x; acc[1] += a.y; acc[2] += a.z; acc[3] += a.w;
    acc[4] += c.x; acc[5] += c.y; acc[6] += c.z; acc[7] += c.w;
  }
  const float inv = 1.0f / den;
  uint4 w4;
  w4.x = pk2(f2bf(acc[0]*inv), f2bf(acc[1]*inv));
  w4.y = pk2(f2bf(acc[2]*inv), f2bf(acc[3]*inv));
  w4.z = pk2(f2bf(acc[4]*inv), f2bf(acc[5]*inv));
  w4.w = pk2(f2bf(acc[6]*inv), f2bf(acc[7]*inv));
  *(uint4*)&O[((size_t)b*1024 + q)*1024 + h*64 + d8] = w4;
}

// ---------------------------------------------------------------------------
extern "C" void kernel_launch(void* const* d_in, const int* in_sizes, int n_in,
                              void* d_out, int out_size, void* d_ws, size_t ws_size,
                              hipStream_t stream) {
  (void)in_sizes; (void)n_in; (void)out_size; (void)ws_size;
  const float* x_in = (const float*)d_in[0];
  const float* norm[5] = { (const float*)d_in[5], (const float*)d_in[10], (const float*)d_in[15],
                           (const float*)d_in[20], (const float*)d_in[25] };
  char* w = (char*)d_ws;
  auto alloc = [&](size_t bytes) { char* p = w; w += (bytes + 255) & ~(size_t)255; return p; };
  ushort_t* qkvT = (ushort_t*)alloc(4ull*3072*1024*2);
  ushort_t* woT  = (ushort_t*)alloc(4ull*1024*1024*2);
  ushort_t* guT  = (ushort_t*)alloc(8192ull*1024*2);
  ushort_t* dnT  = (ushort_t*)alloc(4096ull*1024*2);
  float*    xbuf = (float*)  alloc(2048ull*1024*4);
  ushort_t* xn   = (ushort_t*)alloc(2048ull*1024*2);
  ushort_t* qkv  = (ushort_t*)alloc(2048ull*3072*2);
  ushort_t* attO = (ushort_t*)alloc(2048ull*1024*2);
  ushort_t* hmid = (ushort_t*)alloc(2048ull*4096*2);
  float*  scratch = (float*)alloc(8ull*1024*16*64*4);   // 33.5MB: Pp / Opart (disjoint lifetimes)
  float* Pp    = scratch;        // split-K partials: up to 2 x 8.4MB
  float* Opart = scratch;        // full-attn O partials (4 x 8.4MB)
  float* Lpart = (float*)hmid;   // full-attn l partials (hmid written later, in FFN)

  TPtrs tp;
  for (int l = 0; l < 4; l++) {
    tp.src[l*4 + 0] = (const float*)d_in[6 + l*5];
    tp.src[l*4 + 1] = (const float*)d_in[7 + l*5];
    tp.src[l*4 + 2] = (const float*)d_in[8 + l*5];
    tp.src[l*4 + 3] = (const float*)d_in[9 + l*5];
  }
  tp.src[16] = (const float*)d_in[27];   // w_gate
  tp.src[17] = (const float*)d_in[26];   // w_up
  tp.src[18] = (const float*)d_in[28];   // w_down
  transpose_all<<<7168, 256, 0, stream>>>(tp, qkvT, woT, guT, dnT);

  // prologue: xbuf = x_in, xn = rms(x_in)*norm0
  fused_add_rms<0,1><<<2048, 256, 0, stream>>>(x_in, nullptr, norm[0], xbuf, xn);

  for (int l = 0; l < 4; l++) {
    // QKV: 128x96 tile, grid (32,16)=512 blocks
    gemm_bt<128,96,0,1><<<dim3(3072/96, 2048/128), 256, 0, stream>>>(
        xn, qkvT + (size_t)l*3072*1024, qkv, 2048, 3072, 1024);
    if (l == 0)      attn_col_k         <<<dim3(32, 16, 2), 256, 0, stream>>>(qkv, attO);
    else if (l == 1) attn_flash_k<0,1>  <<<dim3(16, 16, 2), 256, 0, stream>>>(qkv, attO, nullptr, nullptr);
    else if (l == 2) attn_flash_k<1,1>  <<<dim3(16, 16, 2), 256, 0, stream>>>(qkv, attO, nullptr, nullptr);
    else {
      attn_flash_k<2,4><<<dim3(16, 16, 8), 256, 0, stream>>>(qkv, nullptr, Opart, Lpart);
      attn_merge_k<4><<<1024, 256, 0, stream>>>(Opart, Lpart, attO);
    }
    // WO: 128x64 SK2 partials (512 blocks), then fused residual+next-rms
    gemm_bt<128,64,3,2><<<dim3(1024/64, 2048/128, 2), 256, 0, stream>>>(
        attO, woT + (size_t)l*1024*1024, Pp, 2048, 1024, 1024);
    fused_add_rms<2,1><<<2048, 256, 0, stream>>>(xbuf, Pp, norm[l+1 < 4 ? l+1 : 4], xbuf, xn);
  }
  // FFN: fused GU+SwiGLU -> hmid, then down-proj SK2 + fused residual
  gemm_gu_swiglu<<<dim3(4096/128, 2048/128), 256, 0, stream>>>(xn, guT, hmid);
  gemm_bt<128,64,3,2><<<dim3(1024/64, 2048/128, 2), 256, 0, stream>>>(
      hmid, dnT, Pp, 2048, 1024, 4096);
  fused_add_rms<2,0><<<2048, 256, 0, stream>>>(xbuf, Pp, nullptr, (float*)d_out, nullptr);
}